// Round 8
// baseline (337.329 us; speedup 1.0000x reference)
//
#include <hip/hip_runtime.h>
#include <hip/hip_bf16.h>
#include <math.h>

#define BB 64
#define LL 2048
#define HH 512
#define EE 512
#define VV 32000
#define H3 1536

typedef __attribute__((ext_vector_type(8))) __bf16 bf16x8;
typedef __attribute__((ext_vector_type(4))) float f32x4;

__device__ __forceinline__ void ld8(const float* __restrict__ p, float* v) {
  float4 a = *(const float4*)p;
  float4 b = *(const float4*)(p + 4);
  v[0]=a.x; v[1]=a.y; v[2]=a.z; v[3]=a.w;
  v[4]=b.x; v[5]=b.y; v[6]=b.z; v[7]=b.w;
}
__device__ __forceinline__ void ld16(const float* __restrict__ p, float* v) {
  ld8(p, v); ld8(p + 8, v + 8);
}
__device__ __forceinline__ float wsum(float v) {
#pragma unroll
  for (int off = 32; off; off >>= 1) v += __shfl_xor(v, off);
  return v;
}
__device__ __forceinline__ unsigned short f2bf(float f) {
  unsigned int u = __float_as_uint(f);
  u = (u + 0x7FFFu + ((u >> 16) & 1u)) >> 16;
  return (unsigned short)u;
}

// ---------------- K1: GRU gates (R6/R7 form) ----------------------------
__device__ __forceinline__ void k1_proc(
    const float wih[2][8], const float whh[2][8], const float xv[8],
    const float hv[8], int b, int j0, int lane,
    const float* __restrict__ bih, const float* __restrict__ bhh,
    float* __restrict__ gi, float* __restrict__ gh) {
#pragma unroll
  for (int r = 0; r < 2; ++r) {
    float di = 0.f, dh = 0.f;
#pragma unroll
    for (int i = 0; i < 8; ++i) {
      di += wih[r][i] * xv[i];
      dh += whh[r][i] * hv[i];
    }
    di = wsum(di);
    dh = wsum(dh);
    if (lane == 0) {
      gi[b * H3 + j0 + r] = di + bih[j0 + r];
      gh[b * H3 + j0 + r] = dh + bhh[j0 + r];
    }
  }
}

__global__ __launch_bounds__(256) void k1_gates(
    const int* __restrict__ seq, const float* __restrict__ h,
    const float* __restrict__ emb, const float* __restrict__ Wih,
    const float* __restrict__ Whh, const float* __restrict__ bih,
    const float* __restrict__ bhh, float* __restrict__ gi,
    float* __restrict__ gh) {
  int lane = threadIdx.x & 63;
  int wid = blockIdx.x * 4 + (threadIdx.x >> 6);  // 0..1535
  int jp = wid >> 1, bh = wid & 1;
  int j0 = jp * 2;
  float wih[2][8], whh[2][8];
#pragma unroll
  for (int r = 0; r < 2; ++r) {
    ld8(Wih + (size_t)(j0 + r) * EE + lane * 8, wih[r]);
    ld8(Whh + (size_t)(j0 + r) * HH + lane * 8, whh[r]);
  }
  int bs = bh * 32;
  float xvA[8], hvA[8], xvB[8], hvB[8];
  ld8(emb + (size_t)seq[bs] * EE + lane * 8, xvA);
  ld8(h + bs * HH + lane * 8, hvA);
#pragma unroll
  for (int bi = 0; bi < 32; bi += 2) {
    int b = bs + bi;
    ld8(emb + (size_t)seq[b + 1] * EE + lane * 8, xvB);
    ld8(h + (b + 1) * HH + lane * 8, hvB);
    k1_proc(wih, whh, xvA, hvA, b, j0, lane, bih, bhh, gi, gh);
    if (bi + 2 < 32) {
      ld8(emb + (size_t)seq[b + 2] * EE + lane * 8, xvA);
      ld8(h + (b + 2) * HH + lane * 8, hvA);
    }
    k1_proc(wih, whh, xvB, hvB, b + 1, j0, lane, bih, bhh, gi, gh);
  }
}

// ---------------- K3: DIAGNOSTIC x-rep version --------------------------
__device__ __forceinline__ void ldgrp(const float* __restrict__ eb, int w,
                                      int k0, int g, float ev[4][8]) {
#pragma unroll
  for (int q = 0; q < 4; ++q)
    ld8(eb + (size_t)(w + (g * 4 + q) * 4) * HH + k0, ev[q]);
}

__device__ __forceinline__ void procgrp(const float ev[4][8],
                                        const float hv[8], int g, int w,
                                        int lane, float* __restrict__ srow,
                                        float& m, float& s, float c[8]) {
  float d[4];
#pragma unroll
  for (int q = 0; q < 4; ++q) {
    float dd = 0.f;
#pragma unroll
    for (int j = 0; j < 8; ++j) dd += hv[j] * ev[q][j];
    d[q] = wsum(dd);
  }
  if (lane == 0) {
#pragma unroll
    for (int q = 0; q < 4; ++q) srow[w + (g * 4 + q) * 4] = d[q];
  }
  float gmax = fmaxf(fmaxf(d[0], d[1]), fmaxf(d[2], d[3]));
  float mn = fmaxf(m, gmax);
  float sc = __expf(m - mn);
  s *= sc;
#pragma unroll
  for (int j = 0; j < 8; ++j) c[j] *= sc;
  m = mn;
#pragma unroll
  for (int q = 0; q < 4; ++q) {
    float wq = __expf(d[q] - m);
    s += wq;
#pragma unroll
    for (int j = 0; j < 8; ++j) c[j] += wq * ev[q][j];
  }
}

__global__ __launch_bounds__(256) void k3_attn(
    const float* __restrict__ enc0, const float* __restrict__ gi0,
    const float* __restrict__ gh0, const float* __restrict__ h0,
    const float* __restrict__ feed0, float* __restrict__ cat0,
    float* __restrict__ out1_0, float* __restrict__ out3_0,
    float* __restrict__ scores0, float* __restrict__ pm0,
    float* __restrict__ ps0, float* __restrict__ pc0,
    int rep, long long zoff) {
  int b = blockIdx.y, ch = blockIdx.x;
  int w = threadIdx.x >> 6, lane = threadIdx.x & 63;
  int k0 = lane * 8;
  __shared__ float sm[4], ssum[4];
  __shared__ float scx[4][512];

  for (int r0 = 0; r0 < rep; ++r0) {
    // zoff==0 at runtime; opaque to compiler -> loads/stores re-issued per rep
    size_t zo = (size_t)((long long)r0 * zoff);
    const float* enc = enc0 + zo;
    const float* gi = gi0 + zo;
    const float* gh = gh0 + zo;
    const float* h = h0 + zo;
    const float* feed = feed0 + zo;
    float* cat = cat0 + zo;
    float* out1 = out1_0 + zo;
    float* out3 = out3_0 + zo;
    float* scores = scores0 + zo;
    float* pm = pm0 + zo;
    float* ps = ps0 + zo;
    float* pc = pc0 + zo;

    float hv[8];
    {
      float gr[8], gz[8], gn[8], hr[8], hz[8], hn_[8], hh[8];
      const float* gib = gi + b * H3;
      const float* ghb = gh + b * H3;
      ld8(gib + k0, gr); ld8(gib + 512 + k0, gz); ld8(gib + 1024 + k0, gn);
      ld8(ghb + k0, hr); ld8(ghb + 512 + k0, hz); ld8(ghb + 1024 + k0, hn_);
      ld8(h + b * HH + k0, hh);
#pragma unroll
      for (int i = 0; i < 8; ++i) {
        float rr = 1.f / (1.f + __expf(-(gr[i] + hr[i])));
        float z = 1.f / (1.f + __expf(-(gz[i] + hz[i])));
        float n = tanhf(gn[i] + rr * hn_[i]);
        hv[i] = (1.f - z) * n + z * hh[i];
      }
      if (ch == 0 && w == 0) {
        float fv[8];
        ld8(feed + b * HH + k0, fv);
#pragma unroll
        for (int i = 0; i < 8; ++i) {
          out1[b * HH + k0 + i] = hv[i];
          cat[b * 1024 + k0 + i] = hv[i];
          out3[b * HH + k0 + i] = fv[i];
        }
      }
    }

    float m = -INFINITY, s = 0.f, c[8];
#pragma unroll
    for (int j = 0; j < 8; ++j) c[j] = 0.f;
    const float* eb = enc + ((size_t)b * LL + ch * 128) * HH;
    float* srow = scores + b * LL + ch * 128;

    float evA[4][8], evB[4][8];
    ldgrp(eb, w, k0, 0, evA);
#pragma unroll
    for (int g = 0; g < 8; g += 2) {
      if (g + 1 < 8) ldgrp(eb, w, k0, g + 1, evB);
      procgrp(evA, hv, g, w, lane, srow, m, s, c);
      if (g + 2 < 8) ldgrp(eb, w, k0, g + 2, evA);
      procgrp(evB, hv, g + 1, w, lane, srow, m, s, c);
    }

    if (lane == 0) { sm[w] = m; ssum[w] = s; }
#pragma unroll
    for (int j = 0; j < 8; ++j) scx[w][k0 + j] = c[j];
    __syncthreads();
    float mb = fmaxf(fmaxf(sm[0], sm[1]), fmaxf(sm[2], sm[3]));
    int t = threadIdx.x;
    if (t == 0) {
      float sb = 0.f;
#pragma unroll
      for (int w2 = 0; w2 < 4; ++w2) sb += ssum[w2] * __expf(sm[w2] - mb);
      pm[b * 16 + ch] = mb;
      ps[b * 16 + ch] = sb;
    }
    for (int k = t; k < 512; k += 256) {
      float v = 0.f;
#pragma unroll
      for (int w2 = 0; w2 < 4; ++w2) v += scx[w2][k] * __expf(sm[w2] - mb);
      pc[(size_t)(b * 16 + ch) * 512 + k] = v;
    }
    __syncthreads();  // protect sm/ssum/scx for next rep
  }
}

// K45: per-batch combine -> ctx (cat[:,512:]) AND attn-weights output.
__global__ __launch_bounds__(256) void k45_ctx(
    const float* __restrict__ pm, const float* __restrict__ ps,
    const float* __restrict__ pc, const float* __restrict__ scores,
    float* __restrict__ cat, float* __restrict__ out2) {
  int b = blockIdx.x;
  int tid = threadIdx.x;
  float mb = -INFINITY;
#pragma unroll
  for (int ch = 0; ch < 16; ++ch) mb = fmaxf(mb, pm[b * 16 + ch]);
  float e[16];
  float den = 0.f;
#pragma unroll
  for (int ch = 0; ch < 16; ++ch) {
    e[ch] = __expf(pm[b * 16 + ch] - mb);
    den += ps[b * 16 + ch] * e[ch];
  }
  for (int k = tid; k < 512; k += 256) {
    float v = 0.f;
#pragma unroll
    for (int ch = 0; ch < 16; ++ch)
      v += pc[(size_t)(b * 16 + ch) * 512 + k] * e[ch];
    cat[b * 1024 + 512 + k] = v / den;
  }
  float inv = 1.f / den;
  for (int t = tid; t < LL; t += 256) {
    out2[b * LL + t] = __expf(scores[b * LL + t] - mb) * inv;
  }
}

// K6: concat_output = tanh([h_new, ctx] @ W_concat^T + b_concat) -> bf16
__global__ __launch_bounds__(256) void k6_concat(
    const float* __restrict__ cat, const float* __restrict__ Wc,
    const float* __restrict__ bc, unsigned short* __restrict__ co_bf) {
  int lane = threadIdx.x & 63;
  int wid = blockIdx.x * 4 + (threadIdx.x >> 6);  // 0..4095
  int k = wid >> 3, bg = wid & 7;
  float wv[16];
  ld16(Wc + (size_t)k * 1024 + lane * 16, wv);
  float bk = bc[k];
  for (int b = bg * 8; b < bg * 8 + 8; ++b) {
    float cv[16];
    ld16(cat + b * 1024 + lane * 16, cv);
    float d = 0.f;
#pragma unroll
    for (int i = 0; i < 16; ++i) d += wv[i] * cv[i];
    d = wsum(d);
    if (lane == 0) co_bf[b * HH + k] = f2bf(tanhf(d + bk));
  }
}

// K7 (MFMA, proven R4 form): out0 = co @ W_out^T + b_out.
__global__ __launch_bounds__(256) void k7_out(
    const unsigned short* __restrict__ co_bf, const float* __restrict__ Wo,
    const float* __restrict__ bo, float* __restrict__ out0) {
  int t = threadIdx.x;
  int lane = t & 63, w = t >> 6;
  int v0 = blockIdx.x * 64 + w * 16;
  int l15 = lane & 15;
  int kbase = (lane >> 4) * 8;
  int vrow = v0 + l15;
  const float* wrow = Wo + (size_t)vrow * HH;

  f32x4 acc[4];
#pragma unroll
  for (int j = 0; j < 4; ++j) acc[j] = (f32x4){0.f, 0.f, 0.f, 0.f};

  for (int ks = 0; ks < HH; ks += 32) {
    int k = ks + kbase;
    float4 wa = *(const float4*)(wrow + k);
    float4 wb = *(const float4*)(wrow + k + 4);
    union { unsigned short u[8]; bf16x8 v; } B;
    B.u[0] = f2bf(wa.x); B.u[1] = f2bf(wa.y);
    B.u[2] = f2bf(wa.z); B.u[3] = f2bf(wa.w);
    B.u[4] = f2bf(wb.x); B.u[5] = f2bf(wb.y);
    B.u[6] = f2bf(wb.z); B.u[7] = f2bf(wb.w);
#pragma unroll
    for (int j = 0; j < 4; ++j) {
      bf16x8 A = *(const bf16x8*)(co_bf + (size_t)(j * 16 + l15) * HH + k);
      acc[j] = __builtin_amdgcn_mfma_f32_16x16x32_bf16(A, B.v, acc[j], 0, 0, 0);
    }
  }

  float bias = bo[vrow];
#pragma unroll
  for (int j = 0; j < 4; ++j) {
    int b0 = j * 16 + (lane >> 4) * 4;
#pragma unroll
    for (int r = 0; r < 4; ++r) {
      out0[(size_t)(b0 + r) * VV + vrow] = acc[j][r] + bias;
    }
  }
}

extern "C" void kernel_launch(void* const* d_in, const int* in_sizes, int n_in,
                              void* d_out, int out_size, void* d_ws,
                              size_t ws_size, hipStream_t stream) {
  const int* seq = (const int*)d_in[0];
  const float* last_hidden = (const float*)d_in[1];
  const float* enc = (const float*)d_in[2];
  // d_in[3] encoder_labels unused
  const float* feed = (const float*)d_in[4];
  const float* emb = (const float*)d_in[5];
  const float* Wih = (const float*)d_in[6];
  const float* Whh = (const float*)d_in[7];
  const float* bih = (const float*)d_in[8];
  const float* bhh = (const float*)d_in[9];
  const float* Wc = (const float*)d_in[10];
  const float* bc = (const float*)d_in[11];
  const float* Wo = (const float*)d_in[12];
  const float* bo = (const float*)d_in[13];

  float* out = (float*)d_out;
  float* out0 = out;            // B*V
  float* out1 = out + 2048000;  // B*H
  float* out2 = out + 2080768;  // B*L
  float* out3 = out + 2211840;  // B*H

  float* ws = (float*)d_ws;
  float* gi = ws;                  // 98304
  float* gh = gi + 98304;          // 98304
  float* cat = gh + 98304;         // 65536 (h_new | context)
  float* scores = cat + 65536;     // 131072
  float* pm = scores + 131072;     // 1024
  float* ps = pm + 1024;           // 1024
  float* pc = ps + 1024;           // 524288
  unsigned short* co_bf = (unsigned short*)(pc + 524288);  // 32768 u16

  hipLaunchKernelGGL(k1_gates, dim3(384), dim3(256), 0, stream,
                     seq, last_hidden, emb, Wih, Whh, bih, bhh, gi, gh);
  // DIAGNOSTIC: rep=6 internal repeats, zoff=0 (opaque zero offset)
  hipLaunchKernelGGL(k3_attn, dim3(16, 64), dim3(256), 0, stream,
                     enc, gi, gh, last_hidden, feed, cat, out1, out3,
                     scores, pm, ps, pc, 6, (long long)0);
  hipLaunchKernelGGL(k45_ctx, dim3(64), dim3(256), 0, stream,
                     pm, ps, pc, scores, cat, out2);
  hipLaunchKernelGGL(k6_concat, dim3(1024), dim3(256), 0, stream,
                     cat, Wc, bc, co_bf);
  hipLaunchKernelGGL(k7_out, dim3(500), dim3(256), 0, stream,
                     co_bf, Wo, bo, out0);
}

// Round 9
// 280.508 us; speedup vs baseline: 1.2026x; 1.2026x over previous
//
#include <hip/hip_runtime.h>
#include <hip/hip_bf16.h>
#include <math.h>

#define BB 64
#define LL 2048
#define HH 512
#define EE 512
#define VV 32000
#define H3 1536

typedef __attribute__((ext_vector_type(8))) __bf16 bf16x8;
typedef __attribute__((ext_vector_type(4))) float f32x4;

__device__ __forceinline__ void ld8(const float* __restrict__ p, float* v) {
  float4 a = *(const float4*)p;
  float4 b = *(const float4*)(p + 4);
  v[0]=a.x; v[1]=a.y; v[2]=a.z; v[3]=a.w;
  v[4]=b.x; v[5]=b.y; v[6]=b.z; v[7]=b.w;
}
__device__ __forceinline__ void ld16(const float* __restrict__ p, float* v) {
  ld8(p, v); ld8(p + 8, v + 8);
}
__device__ __forceinline__ float wsum(float v) {
#pragma unroll
  for (int off = 32; off; off >>= 1) v += __shfl_xor(v, off);
  return v;
}
__device__ __forceinline__ unsigned short f2bf(float f) {
  unsigned int u = __float_as_uint(f);
  u = (u + 0x7FFFu + ((u >> 16) & 1u)) >> 16;
  return (unsigned short)u;
}

// ---------------- K1: GRU gates (R6/R7 form, proven) --------------------
__device__ __forceinline__ void k1_proc(
    const float wih[2][8], const float whh[2][8], const float xv[8],
    const float hv[8], int b, int j0, int lane,
    const float* __restrict__ bih, const float* __restrict__ bhh,
    float* __restrict__ gi, float* __restrict__ gh) {
#pragma unroll
  for (int r = 0; r < 2; ++r) {
    float di = 0.f, dh = 0.f;
#pragma unroll
    for (int i = 0; i < 8; ++i) {
      di += wih[r][i] * xv[i];
      dh += whh[r][i] * hv[i];
    }
    di = wsum(di);
    dh = wsum(dh);
    if (lane == 0) {
      gi[b * H3 + j0 + r] = di + bih[j0 + r];
      gh[b * H3 + j0 + r] = dh + bhh[j0 + r];
    }
  }
}

__global__ __launch_bounds__(256) void k1_gates(
    const int* __restrict__ seq, const float* __restrict__ h,
    const float* __restrict__ emb, const float* __restrict__ Wih,
    const float* __restrict__ Whh, const float* __restrict__ bih,
    const float* __restrict__ bhh, float* __restrict__ gi,
    float* __restrict__ gh) {
  int lane = threadIdx.x & 63;
  int wid = blockIdx.x * 4 + (threadIdx.x >> 6);  // 0..1535
  int jp = wid >> 1, bh = wid & 1;
  int j0 = jp * 2;
  float wih[2][8], whh[2][8];
#pragma unroll
  for (int r = 0; r < 2; ++r) {
    ld8(Wih + (size_t)(j0 + r) * EE + lane * 8, wih[r]);
    ld8(Whh + (size_t)(j0 + r) * HH + lane * 8, whh[r]);
  }
  int bs = bh * 32;
  float xvA[8], hvA[8], xvB[8], hvB[8];
  ld8(emb + (size_t)seq[bs] * EE + lane * 8, xvA);
  ld8(h + bs * HH + lane * 8, hvA);
#pragma unroll
  for (int bi = 0; bi < 32; bi += 2) {
    int b = bs + bi;
    ld8(emb + (size_t)seq[b + 1] * EE + lane * 8, xvB);
    ld8(h + (b + 1) * HH + lane * 8, hvB);
    k1_proc(wih, whh, xvA, hvA, b, j0, lane, bih, bhh, gi, gh);
    if (bi + 2 < 32) {
      ld8(emb + (size_t)seq[b + 2] * EE + lane * 8, xvA);
      ld8(h + (b + 2) * HH + lane * 8, hvA);
    }
    k1_proc(wih, whh, xvB, hvB, b + 1, j0, lane, bih, bhh, gi, gh);
  }
}

// ---------------- K3: lean-VGPR, 3-deep pipelined streaming -------------
// 2 rows per group, 3 buffers (48 ev regs); __launch_bounds__(256,4)
// forces VGPR<=128 -> 4 waves/SIMD resident (was 2 at VGPR=204).
__device__ __forceinline__ void ldg2(const float* __restrict__ eb, int w,
                                     int k0, int g, float ev[2][8]) {
#pragma unroll
  for (int q = 0; q < 2; ++q)
    ld8(eb + (size_t)(w + (g * 2 + q) * 4) * HH + k0, ev[q]);
}

__device__ __forceinline__ void proc2(const float ev[2][8],
                                      const float hv[8], int g, int w,
                                      int lane, float* __restrict__ srow,
                                      float& m, float& s, float c[8]) {
  float d0 = 0.f, d1 = 0.f;
#pragma unroll
  for (int j = 0; j < 8; ++j) {
    d0 += hv[j] * ev[0][j];
    d1 += hv[j] * ev[1][j];
  }
  d0 = wsum(d0);
  d1 = wsum(d1);
  if (lane == 0) {
    srow[w + (g * 2) * 4] = d0;
    srow[w + (g * 2 + 1) * 4] = d1;
  }
  float mn = fmaxf(m, fmaxf(d0, d1));
  float sc = __expf(m - mn);  // 1.0 when max unchanged
  s *= sc;
#pragma unroll
  for (int j = 0; j < 8; ++j) c[j] *= sc;
  m = mn;
  float w0 = __expf(d0 - m), w1 = __expf(d1 - m);
  s += w0 + w1;
#pragma unroll
  for (int j = 0; j < 8; ++j) c[j] += w0 * ev[0][j] + w1 * ev[1][j];
}

__global__ __launch_bounds__(256, 4) void k3_attn(
    const float* __restrict__ enc, const float* __restrict__ gi,
    const float* __restrict__ gh, const float* __restrict__ h,
    const float* __restrict__ feed, float* __restrict__ cat,
    float* __restrict__ out1, float* __restrict__ out3,
    float* __restrict__ scores, float* __restrict__ pm,
    float* __restrict__ ps, float* __restrict__ pc) {
  int b = blockIdx.y, ch = blockIdx.x;
  int w = threadIdx.x >> 6, lane = threadIdx.x & 63;
  int k0 = lane * 8;

  // recompute h_new[b][k0..k0+7] (identical across the 4 waves)
  float hv[8];
  {
    float gr[8], gz[8], gn[8], hr[8], hz[8], hn_[8], hh[8];
    const float* gib = gi + b * H3;
    const float* ghb = gh + b * H3;
    ld8(gib + k0, gr); ld8(gib + 512 + k0, gz); ld8(gib + 1024 + k0, gn);
    ld8(ghb + k0, hr); ld8(ghb + 512 + k0, hz); ld8(ghb + 1024 + k0, hn_);
    ld8(h + b * HH + k0, hh);
#pragma unroll
    for (int i = 0; i < 8; ++i) {
      float r = 1.f / (1.f + __expf(-(gr[i] + hr[i])));
      float z = 1.f / (1.f + __expf(-(gz[i] + hz[i])));
      float n = tanhf(gn[i] + r * hn_[i]);
      hv[i] = (1.f - z) * n + z * hh[i];
    }
    if (ch == 0 && w == 0) {
      float fv[8];
      ld8(feed + b * HH + k0, fv);
#pragma unroll
      for (int i = 0; i < 8; ++i) {
        out1[b * HH + k0 + i] = hv[i];
        cat[b * 1024 + k0 + i] = hv[i];
        out3[b * HH + k0 + i] = fv[i];
      }
    }
  }

  float m = -INFINITY, s = 0.f, c[8];
#pragma unroll
  for (int j = 0; j < 8; ++j) c[j] = 0.f;
  const float* eb = enc + ((size_t)b * LL + ch * 128) * HH;
  float* srow = scores + b * LL + ch * 128;

  // 3-deep rotation over 16 groups of 2 rows
  float ev[3][2][8];
  ldg2(eb, w, k0, 0, ev[0]);
  ldg2(eb, w, k0, 1, ev[1]);
  ldg2(eb, w, k0, 2, ev[2]);
#pragma unroll
  for (int g = 0; g < 16; ++g) {
    proc2(ev[g % 3], hv, g, w, lane, srow, m, s, c);
    if (g + 3 < 16) ldg2(eb, w, k0, g + 3, ev[g % 3]);
  }

  __shared__ float sm[4], ssum[4];
  __shared__ float scx[4][512];
  if (lane == 0) { sm[w] = m; ssum[w] = s; }
#pragma unroll
  for (int j = 0; j < 8; ++j) scx[w][k0 + j] = c[j];
  __syncthreads();
  float mb = fmaxf(fmaxf(sm[0], sm[1]), fmaxf(sm[2], sm[3]));
  int t = threadIdx.x;
  if (t == 0) {
    float sb = 0.f;
#pragma unroll
    for (int w2 = 0; w2 < 4; ++w2) sb += ssum[w2] * __expf(sm[w2] - mb);
    pm[b * 16 + ch] = mb;
    ps[b * 16 + ch] = sb;
  }
  for (int k = t; k < 512; k += 256) {
    float v = 0.f;
#pragma unroll
    for (int w2 = 0; w2 < 4; ++w2) v += scx[w2][k] * __expf(sm[w2] - mb);
    pc[(size_t)(b * 16 + ch) * 512 + k] = v;
  }
}

// K45: per-batch combine -> ctx (cat[:,512:]) AND attn-weights output.
__global__ __launch_bounds__(256) void k45_ctx(
    const float* __restrict__ pm, const float* __restrict__ ps,
    const float* __restrict__ pc, const float* __restrict__ scores,
    float* __restrict__ cat, float* __restrict__ out2) {
  int b = blockIdx.x;
  int tid = threadIdx.x;
  float mb = -INFINITY;
#pragma unroll
  for (int ch = 0; ch < 16; ++ch) mb = fmaxf(mb, pm[b * 16 + ch]);
  float e[16];
  float den = 0.f;
#pragma unroll
  for (int ch = 0; ch < 16; ++ch) {
    e[ch] = __expf(pm[b * 16 + ch] - mb);
    den += ps[b * 16 + ch] * e[ch];
  }
  for (int k = tid; k < 512; k += 256) {
    float v = 0.f;
#pragma unroll
    for (int ch = 0; ch < 16; ++ch)
      v += pc[(size_t)(b * 16 + ch) * 512 + k] * e[ch];
    cat[b * 1024 + 512 + k] = v / den;
  }
  float inv = 1.f / den;
  for (int t = tid; t < LL; t += 256) {
    out2[b * LL + t] = __expf(scores[b * LL + t] - mb) * inv;
  }
}

// K6: concat_output = tanh([h_new, ctx] @ W_concat^T + b_concat) -> bf16
__global__ __launch_bounds__(256) void k6_concat(
    const float* __restrict__ cat, const float* __restrict__ Wc,
    const float* __restrict__ bc, unsigned short* __restrict__ co_bf) {
  int lane = threadIdx.x & 63;
  int wid = blockIdx.x * 4 + (threadIdx.x >> 6);  // 0..4095
  int k = wid >> 3, bg = wid & 7;
  float wv[16];
  ld16(Wc + (size_t)k * 1024 + lane * 16, wv);
  float bk = bc[k];
  for (int b = bg * 8; b < bg * 8 + 8; ++b) {
    float cv[16];
    ld16(cat + b * 1024 + lane * 16, cv);
    float d = 0.f;
#pragma unroll
    for (int i = 0; i < 16; ++i) d += wv[i] * cv[i];
    d = wsum(d);
    if (lane == 0) co_bf[b * HH + k] = f2bf(tanhf(d + bk));
  }
}

// K7 (MFMA, proven R4 form): out0 = co @ W_out^T + b_out.
__global__ __launch_bounds__(256) void k7_out(
    const unsigned short* __restrict__ co_bf, const float* __restrict__ Wo,
    const float* __restrict__ bo, float* __restrict__ out0) {
  int t = threadIdx.x;
  int lane = t & 63, w = t >> 6;
  int v0 = blockIdx.x * 64 + w * 16;
  int l15 = lane & 15;
  int kbase = (lane >> 4) * 8;
  int vrow = v0 + l15;
  const float* wrow = Wo + (size_t)vrow * HH;

  f32x4 acc[4];
#pragma unroll
  for (int j = 0; j < 4; ++j) acc[j] = (f32x4){0.f, 0.f, 0.f, 0.f};

  for (int ks = 0; ks < HH; ks += 32) {
    int k = ks + kbase;
    float4 wa = *(const float4*)(wrow + k);
    float4 wb = *(const float4*)(wrow + k + 4);
    union { unsigned short u[8]; bf16x8 v; } B;
    B.u[0] = f2bf(wa.x); B.u[1] = f2bf(wa.y);
    B.u[2] = f2bf(wa.z); B.u[3] = f2bf(wa.w);
    B.u[4] = f2bf(wb.x); B.u[5] = f2bf(wb.y);
    B.u[6] = f2bf(wb.z); B.u[7] = f2bf(wb.w);
#pragma unroll
    for (int j = 0; j < 4; ++j) {
      bf16x8 A = *(const bf16x8*)(co_bf + (size_t)(j * 16 + l15) * HH + k);
      acc[j] = __builtin_amdgcn_mfma_f32_16x16x32_bf16(A, B.v, acc[j], 0, 0, 0);
    }
  }

  float bias = bo[vrow];
#pragma unroll
  for (int j = 0; j < 4; ++j) {
    int b0 = j * 16 + (lane >> 4) * 4;
#pragma unroll
    for (int r = 0; r < 4; ++r) {
      out0[(size_t)(b0 + r) * VV + vrow] = acc[j][r] + bias;
    }
  }
}

extern "C" void kernel_launch(void* const* d_in, const int* in_sizes, int n_in,
                              void* d_out, int out_size, void* d_ws,
                              size_t ws_size, hipStream_t stream) {
  const int* seq = (const int*)d_in[0];
  const float* last_hidden = (const float*)d_in[1];
  const float* enc = (const float*)d_in[2];
  // d_in[3] encoder_labels unused
  const float* feed = (const float*)d_in[4];
  const float* emb = (const float*)d_in[5];
  const float* Wih = (const float*)d_in[6];
  const float* Whh = (const float*)d_in[7];
  const float* bih = (const float*)d_in[8];
  const float* bhh = (const float*)d_in[9];
  const float* Wc = (const float*)d_in[10];
  const float* bc = (const float*)d_in[11];
  const float* Wo = (const float*)d_in[12];
  const float* bo = (const float*)d_in[13];

  float* out = (float*)d_out;
  float* out0 = out;            // B*V
  float* out1 = out + 2048000;  // B*H
  float* out2 = out + 2080768;  // B*L
  float* out3 = out + 2211840;  // B*H

  float* ws = (float*)d_ws;
  float* gi = ws;                  // 98304
  float* gh = gi + 98304;          // 98304
  float* cat = gh + 98304;         // 65536 (h_new | context)
  float* scores = cat + 65536;     // 131072
  float* pm = scores + 131072;     // 1024
  float* ps = pm + 1024;           // 1024
  float* pc = ps + 1024;           // 524288
  unsigned short* co_bf = (unsigned short*)(pc + 524288);  // 32768 u16

  hipLaunchKernelGGL(k1_gates, dim3(384), dim3(256), 0, stream,
                     seq, last_hidden, emb, Wih, Whh, bih, bhh, gi, gh);
  hipLaunchKernelGGL(k3_attn, dim3(16, 64), dim3(256), 0, stream,
                     enc, gi, gh, last_hidden, feed, cat, out1, out3,
                     scores, pm, ps, pc);
  hipLaunchKernelGGL(k45_ctx, dim3(64), dim3(256), 0, stream,
                     pm, ps, pc, scores, cat, out2);
  hipLaunchKernelGGL(k6_concat, dim3(1024), dim3(256), 0, stream,
                     cat, Wc, bc, co_bf);
  hipLaunchKernelGGL(k7_out, dim3(500), dim3(256), 0, stream,
                     co_bf, Wo, bo, out0);
}

// Round 10
// 160.843 us; speedup vs baseline: 2.0973x; 1.7440x over previous
//
#include <hip/hip_runtime.h>
#include <hip/hip_bf16.h>
#include <math.h>

#define BB 64
#define LL 2048
#define HH 512
#define EE 512
#define VV 32000
#define H3 1536
#define CH_ROWS 32
#define NCH 64  // LL / CH_ROWS

typedef __attribute__((ext_vector_type(8))) __bf16 bf16x8;
typedef __attribute__((ext_vector_type(4))) float f32x4;

__device__ __forceinline__ void ld8(const float* __restrict__ p, float* v) {
  float4 a = *(const float4*)p;
  float4 b = *(const float4*)(p + 4);
  v[0]=a.x; v[1]=a.y; v[2]=a.z; v[3]=a.w;
  v[4]=b.x; v[5]=b.y; v[6]=b.z; v[7]=b.w;
}
__device__ __forceinline__ void ld16(const float* __restrict__ p, float* v) {
  ld8(p, v); ld8(p + 8, v + 8);
}
__device__ __forceinline__ float wsum(float v) {
#pragma unroll
  for (int off = 32; off; off >>= 1) v += __shfl_xor(v, off);
  return v;
}
__device__ __forceinline__ unsigned short f2bf(float f) {
  unsigned int u = __float_as_uint(f);
  u = (u + 0x7FFFu + ((u >> 16) & 1u)) >> 16;
  return (unsigned short)u;
}

// ---------------- K1: GRU gates (R6-proven) -----------------------------
__device__ __forceinline__ void k1_proc(
    const float wih[2][8], const float whh[2][8], const float xv[8],
    const float hv[8], int b, int j0, int lane,
    const float* __restrict__ bih, const float* __restrict__ bhh,
    float* __restrict__ gi, float* __restrict__ gh) {
#pragma unroll
  for (int r = 0; r < 2; ++r) {
    float di = 0.f, dh = 0.f;
#pragma unroll
    for (int i = 0; i < 8; ++i) {
      di += wih[r][i] * xv[i];
      dh += whh[r][i] * hv[i];
    }
    di = wsum(di);
    dh = wsum(dh);
    if (lane == 0) {
      gi[b * H3 + j0 + r] = di + bih[j0 + r];
      gh[b * H3 + j0 + r] = dh + bhh[j0 + r];
    }
  }
}

__global__ __launch_bounds__(256) void k1_gates(
    const int* __restrict__ seq, const float* __restrict__ h,
    const float* __restrict__ emb, const float* __restrict__ Wih,
    const float* __restrict__ Whh, const float* __restrict__ bih,
    const float* __restrict__ bhh, float* __restrict__ gi,
    float* __restrict__ gh) {
  int lane = threadIdx.x & 63;
  int wid = blockIdx.x * 4 + (threadIdx.x >> 6);  // 0..1535
  int jp = wid >> 1, bh = wid & 1;
  int j0 = jp * 2;
  float wih[2][8], whh[2][8];
#pragma unroll
  for (int r = 0; r < 2; ++r) {
    ld8(Wih + (size_t)(j0 + r) * EE + lane * 8, wih[r]);
    ld8(Whh + (size_t)(j0 + r) * HH + lane * 8, whh[r]);
  }
  int bs = bh * 32;
  float xvA[8], hvA[8], xvB[8], hvB[8];
  ld8(emb + (size_t)seq[bs] * EE + lane * 8, xvA);
  ld8(h + bs * HH + lane * 8, hvA);
#pragma unroll
  for (int bi = 0; bi < 32; bi += 2) {
    int b = bs + bi;
    ld8(emb + (size_t)seq[b + 1] * EE + lane * 8, xvB);
    ld8(h + (b + 1) * HH + lane * 8, hvB);
    k1_proc(wih, whh, xvA, hvA, b, j0, lane, bih, bhh, gi, gh);
    if (bi + 2 < 32) {
      ld8(emb + (size_t)seq[b + 2] * EE + lane * 8, xvA);
      ld8(h + (b + 2) * HH + lane * 8, hvA);
    }
    k1_proc(wih, whh, xvB, hvB, b + 1, j0, lane, bih, bhh, gi, gh);
  }
}

// ---------------- K2: h_new + out1/out3 + cat[:, :512] (R4-proven) ------
__global__ __launch_bounds__(256) void k2_hnew(
    const float* __restrict__ gi, const float* __restrict__ gh,
    const float* __restrict__ h, const float* __restrict__ feed,
    float* __restrict__ cat, float* __restrict__ out1,
    float* __restrict__ out3) {
  int t = blockIdx.x * 256 + threadIdx.x;  // 32768
  int b = t >> 9, k = t & 511;
  const float* gib = gi + b * H3;
  const float* ghb = gh + b * H3;
  float r = 1.f / (1.f + __expf(-(gib[k] + ghb[k])));
  float z = 1.f / (1.f + __expf(-(gib[k + HH] + ghb[k + HH])));
  float n = tanhf(gib[k + 2 * HH] + r * ghb[k + 2 * HH]);
  float hn = (1.f - z) * n + z * h[t];
  cat[b * 1024 + k] = hn;
  out1[t] = hn;
  out3[t] = feed[t];
}

// ---------------- K3: LDS-staged streaming attention --------------------
// grid (NCH, BB) x 256 thr. Block stages a 32-row (64 KB) enc chunk into
// LDS with 8-deep float4 batches, then computes scores + online-softmax
// partial context from LDS. Lane owns k-slices {4L..4L+3, 256+4L..+3}
// -> every ds_read_b128 covers all 32 banks uniformly (conflict-free).
__global__ __launch_bounds__(256) void k3_attn(
    const float* __restrict__ enc, const float* __restrict__ cat,
    float* __restrict__ scores, float* __restrict__ pm,
    float* __restrict__ ps, float* __restrict__ pc) {
  __shared__ float lds[CH_ROWS * HH];  // 64 KB
  int b = blockIdx.y, ch = blockIdx.x;
  int tid = threadIdx.x, w = tid >> 6, lane = tid & 63;

  const float* eb = enc + ((size_t)b * LL + ch * CH_ROWS) * HH;
  float4 h4a = *(const float4*)(cat + b * 1024 + 4 * lane);
  float4 h4b = *(const float4*)(cat + b * 1024 + 256 + 4 * lane);

  {  // stage 64 KB; 16 float4/thread in two 8-deep batches
    const float4* src = (const float4*)eb;
    float4* dst = (float4*)lds;
    float4 buf[8];
#pragma unroll
    for (int i = 0; i < 8; ++i) buf[i] = src[tid + 256 * i];
#pragma unroll
    for (int i = 0; i < 8; ++i) dst[tid + 256 * i] = buf[i];
#pragma unroll
    for (int i = 0; i < 8; ++i) buf[i] = src[tid + 256 * (i + 8)];
#pragma unroll
    for (int i = 0; i < 8; ++i) dst[tid + 256 * (i + 8)] = buf[i];
  }
  __syncthreads();

  float m = -INFINITY, s = 0.f;
  float4 ca = {0.f, 0.f, 0.f, 0.f}, cb = {0.f, 0.f, 0.f, 0.f};
  float* srow = scores + b * LL + ch * CH_ROWS;
#pragma unroll
  for (int j = 0; j < 8; ++j) {
    int r = w + 4 * j;
    float4 ea = *(const float4*)&lds[r * HH + 4 * lane];
    float4 e2 = *(const float4*)&lds[r * HH + 256 + 4 * lane];
    float d = ea.x * h4a.x + ea.y * h4a.y + ea.z * h4a.z + ea.w * h4a.w +
              e2.x * h4b.x + e2.y * h4b.y + e2.z * h4b.z + e2.w * h4b.w;
    d = wsum(d);
    if (lane == 0) srow[r] = d;
    float mn = fmaxf(m, d);
    float sc = __expf(m - mn);   // 1.0 when max unchanged; 0 at first iter
    float wq = __expf(d - mn);
    s = s * sc + wq;
    ca.x = ca.x * sc + wq * ea.x;
    ca.y = ca.y * sc + wq * ea.y;
    ca.z = ca.z * sc + wq * ea.z;
    ca.w = ca.w * sc + wq * ea.w;
    cb.x = cb.x * sc + wq * e2.x;
    cb.y = cb.y * sc + wq * e2.y;
    cb.z = cb.z * sc + wq * e2.z;
    cb.w = cb.w * sc + wq * e2.w;
    m = mn;
  }
  __syncthreads();  // all LDS reads done; safe to reuse as scratch

  float* sm = lds;          // 4
  float* ssum = lds + 4;    // 4
  float* scx = lds + 8;     // 4*512 (16B-aligned: offset 32 B)
  if (lane == 0) { sm[w] = m; ssum[w] = s; }
  ((float4*)(scx + w * 512))[lane] = ca;
  ((float4*)(scx + w * 512 + 256))[lane] = cb;
  __syncthreads();
  float mb = fmaxf(fmaxf(sm[0], sm[1]), fmaxf(sm[2], sm[3]));
  if (tid == 0) {
    float sb = 0.f;
#pragma unroll
    for (int w2 = 0; w2 < 4; ++w2) sb += ssum[w2] * __expf(sm[w2] - mb);
    pm[b * NCH + ch] = mb;
    ps[b * NCH + ch] = sb;
  }
  for (int k = tid; k < 512; k += 256) {
    float v = 0.f;
#pragma unroll
    for (int w2 = 0; w2 < 4; ++w2) v += scx[w2 * 512 + k] * __expf(sm[w2] - mb);
    pc[(size_t)(b * NCH + ch) * 512 + k] = v;
  }
}

// ---------------- K45: combine -> ctx + attn-weights output -------------
__global__ __launch_bounds__(256) void k45_ctx(
    const float* __restrict__ pm, const float* __restrict__ ps,
    const float* __restrict__ pc, const float* __restrict__ scores,
    float* __restrict__ cat, float* __restrict__ out2) {
  int b = blockIdx.x;
  int tid = threadIdx.x;
  float mb = -INFINITY;
#pragma unroll
  for (int ch = 0; ch < NCH; ++ch) mb = fmaxf(mb, pm[b * NCH + ch]);
  float e[NCH];
  float den = 0.f;
#pragma unroll
  for (int ch = 0; ch < NCH; ++ch) {
    e[ch] = __expf(pm[b * NCH + ch] - mb);
    den += ps[b * NCH + ch] * e[ch];
  }
  for (int k = tid; k < 512; k += 256) {
    float v = 0.f;
#pragma unroll
    for (int ch = 0; ch < NCH; ++ch)
      v += pc[(size_t)(b * NCH + ch) * 512 + k] * e[ch];
    cat[b * 1024 + 512 + k] = v / den;
  }
  float inv = 1.f / den;
  for (int t = tid; t < LL; t += 256) {
    out2[b * LL + t] = __expf(scores[b * LL + t] - mb) * inv;
  }
}

// ---------------- K6: concat GEMV -> bf16 (proven) ----------------------
__global__ __launch_bounds__(256) void k6_concat(
    const float* __restrict__ cat, const float* __restrict__ Wc,
    const float* __restrict__ bc, unsigned short* __restrict__ co_bf) {
  int lane = threadIdx.x & 63;
  int wid = blockIdx.x * 4 + (threadIdx.x >> 6);  // 0..4095
  int k = wid >> 3, bg = wid & 7;
  float wv[16];
  ld16(Wc + (size_t)k * 1024 + lane * 16, wv);
  float bk = bc[k];
  for (int b = bg * 8; b < bg * 8 + 8; ++b) {
    float cv[16];
    ld16(cat + b * 1024 + lane * 16, cv);
    float d = 0.f;
#pragma unroll
    for (int i = 0; i < 16; ++i) d += wv[i] * cv[i];
    d = wsum(d);
    if (lane == 0) co_bf[b * HH + k] = f2bf(tanhf(d + bk));
  }
}

// ---------------- K7: MFMA output GEMM (proven R4 form) -----------------
__global__ __launch_bounds__(256) void k7_out(
    const unsigned short* __restrict__ co_bf, const float* __restrict__ Wo,
    const float* __restrict__ bo, float* __restrict__ out0) {
  int t = threadIdx.x;
  int lane = t & 63, w = t >> 6;
  int v0 = blockIdx.x * 64 + w * 16;
  int l15 = lane & 15;
  int kbase = (lane >> 4) * 8;
  int vrow = v0 + l15;
  const float* wrow = Wo + (size_t)vrow * HH;

  f32x4 acc[4];
#pragma unroll
  for (int j = 0; j < 4; ++j) acc[j] = (f32x4){0.f, 0.f, 0.f, 0.f};

  for (int ks = 0; ks < HH; ks += 32) {
    int k = ks + kbase;
    float4 wa = *(const float4*)(wrow + k);
    float4 wb = *(const float4*)(wrow + k + 4);
    union { unsigned short u[8]; bf16x8 v; } B;
    B.u[0] = f2bf(wa.x); B.u[1] = f2bf(wa.y);
    B.u[2] = f2bf(wa.z); B.u[3] = f2bf(wa.w);
    B.u[4] = f2bf(wb.x); B.u[5] = f2bf(wb.y);
    B.u[6] = f2bf(wb.z); B.u[7] = f2bf(wb.w);
#pragma unroll
    for (int j = 0; j < 4; ++j) {
      bf16x8 A = *(const bf16x8*)(co_bf + (size_t)(j * 16 + l15) * HH + k);
      acc[j] = __builtin_amdgcn_mfma_f32_16x16x32_bf16(A, B.v, acc[j], 0, 0, 0);
    }
  }

  float bias = bo[vrow];
#pragma unroll
  for (int j = 0; j < 4; ++j) {
    int b0 = j * 16 + (lane >> 4) * 4;
#pragma unroll
    for (int r = 0; r < 4; ++r) {
      out0[(size_t)(b0 + r) * VV + vrow] = acc[j][r] + bias;
    }
  }
}

extern "C" void kernel_launch(void* const* d_in, const int* in_sizes, int n_in,
                              void* d_out, int out_size, void* d_ws,
                              size_t ws_size, hipStream_t stream) {
  const int* seq = (const int*)d_in[0];
  const float* last_hidden = (const float*)d_in[1];
  const float* enc = (const float*)d_in[2];
  // d_in[3] encoder_labels unused
  const float* feed = (const float*)d_in[4];
  const float* emb = (const float*)d_in[5];
  const float* Wih = (const float*)d_in[6];
  const float* Whh = (const float*)d_in[7];
  const float* bih = (const float*)d_in[8];
  const float* bhh = (const float*)d_in[9];
  const float* Wc = (const float*)d_in[10];
  const float* bc = (const float*)d_in[11];
  const float* Wo = (const float*)d_in[12];
  const float* bo = (const float*)d_in[13];

  float* out = (float*)d_out;
  float* out0 = out;            // B*V
  float* out1 = out + 2048000;  // B*H
  float* out2 = out + 2080768;  // B*L
  float* out3 = out + 2211840;  // B*H

  float* ws = (float*)d_ws;
  float* gi = ws;                  // 98304
  float* gh = gi + 98304;          // 98304
  float* cat = gh + 98304;         // 65536 (h_new | context)
  float* scores = cat + 65536;     // 131072
  float* pm = scores + 131072;     // 4096
  float* ps = pm + 4096;           // 4096
  float* pc = ps + 4096;           // 2097152 (B*NCH*512)
  unsigned short* co_bf = (unsigned short*)(pc + 2097152);  // 32768 u16

  hipLaunchKernelGGL(k1_gates, dim3(384), dim3(256), 0, stream,
                     seq, last_hidden, emb, Wih, Whh, bih, bhh, gi, gh);
  hipLaunchKernelGGL(k2_hnew, dim3(128), dim3(256), 0, stream,
                     gi, gh, last_hidden, feed, cat, out1, out3);
  hipLaunchKernelGGL(k3_attn, dim3(NCH, BB), dim3(256), 0, stream,
                     enc, cat, scores, pm, ps, pc);
  hipLaunchKernelGGL(k45_ctx, dim3(64), dim3(256), 0, stream,
                     pm, ps, pc, scores, cat, out2);
  hipLaunchKernelGGL(k6_concat, dim3(1024), dim3(256), 0, stream,
                     cat, Wc, bc, co_bf);
  hipLaunchKernelGGL(k7_out, dim3(500), dim3(256), 0, stream,
                     co_bf, Wo, bo, out0);
}

// Round 11
// 132.798 us; speedup vs baseline: 2.5402x; 1.2112x over previous
//
#include <hip/hip_runtime.h>
#include <hip/hip_bf16.h>
#include <math.h>

#define BB 64
#define LL 2048
#define HH 512
#define EE 512
#define VV 32000
#define H3 1536
#define CH_ROWS 64
#define NCH 32  // LL / CH_ROWS

typedef __attribute__((ext_vector_type(8))) __bf16 bf16x8;
typedef __attribute__((ext_vector_type(4))) float f32x4;

__device__ __forceinline__ void ld8(const float* __restrict__ p, float* v) {
  float4 a = *(const float4*)p;
  float4 b = *(const float4*)(p + 4);
  v[0]=a.x; v[1]=a.y; v[2]=a.z; v[3]=a.w;
  v[4]=b.x; v[5]=b.y; v[6]=b.z; v[7]=b.w;
}
__device__ __forceinline__ void ld16(const float* __restrict__ p, float* v) {
  ld8(p, v); ld8(p + 8, v + 8);
}
__device__ __forceinline__ float wsum(float v) {
#pragma unroll
  for (int off = 32; off; off >>= 1) v += __shfl_xor(v, off);
  return v;
}
__device__ __forceinline__ unsigned short f2bf(float f) {
  unsigned int u = __float_as_uint(f);
  u = (u + 0x7FFFu + ((u >> 16) & 1u)) >> 16;
  return (unsigned short)u;
}

// ---------------- K1: GRU gates (R6-proven) -----------------------------
__device__ __forceinline__ void k1_proc(
    const float wih[2][8], const float whh[2][8], const float xv[8],
    const float hv[8], int b, int j0, int lane,
    const float* __restrict__ bih, const float* __restrict__ bhh,
    float* __restrict__ gi, float* __restrict__ gh) {
#pragma unroll
  for (int r = 0; r < 2; ++r) {
    float di = 0.f, dh = 0.f;
#pragma unroll
    for (int i = 0; i < 8; ++i) {
      di += wih[r][i] * xv[i];
      dh += whh[r][i] * hv[i];
    }
    di = wsum(di);
    dh = wsum(dh);
    if (lane == 0) {
      gi[b * H3 + j0 + r] = di + bih[j0 + r];
      gh[b * H3 + j0 + r] = dh + bhh[j0 + r];
    }
  }
}

__global__ __launch_bounds__(256) void k1_gates(
    const int* __restrict__ seq, const float* __restrict__ h,
    const float* __restrict__ emb, const float* __restrict__ Wih,
    const float* __restrict__ Whh, const float* __restrict__ bih,
    const float* __restrict__ bhh, float* __restrict__ gi,
    float* __restrict__ gh) {
  int lane = threadIdx.x & 63;
  int wid = blockIdx.x * 4 + (threadIdx.x >> 6);  // 0..1535
  int jp = wid >> 1, bh = wid & 1;
  int j0 = jp * 2;
  float wih[2][8], whh[2][8];
#pragma unroll
  for (int r = 0; r < 2; ++r) {
    ld8(Wih + (size_t)(j0 + r) * EE + lane * 8, wih[r]);
    ld8(Whh + (size_t)(j0 + r) * HH + lane * 8, whh[r]);
  }
  int bs = bh * 32;
  float xvA[8], hvA[8], xvB[8], hvB[8];
  ld8(emb + (size_t)seq[bs] * EE + lane * 8, xvA);
  ld8(h + bs * HH + lane * 8, hvA);
#pragma unroll
  for (int bi = 0; bi < 32; bi += 2) {
    int b = bs + bi;
    ld8(emb + (size_t)seq[b + 1] * EE + lane * 8, xvB);
    ld8(h + (b + 1) * HH + lane * 8, hvB);
    k1_proc(wih, whh, xvA, hvA, b, j0, lane, bih, bhh, gi, gh);
    if (bi + 2 < 32) {
      ld8(emb + (size_t)seq[b + 2] * EE + lane * 8, xvA);
      ld8(h + (b + 2) * HH + lane * 8, hvA);
    }
    k1_proc(wih, whh, xvB, hvB, b + 1, j0, lane, bih, bhh, gi, gh);
  }
}

// ---------------- K2: h_new + out1/out3 + cat[:, :512] (R4-proven) ------
__global__ __launch_bounds__(256) void k2_hnew(
    const float* __restrict__ gi, const float* __restrict__ gh,
    const float* __restrict__ h, const float* __restrict__ feed,
    float* __restrict__ cat, float* __restrict__ out1,
    float* __restrict__ out3) {
  int t = blockIdx.x * 256 + threadIdx.x;  // 32768
  int b = t >> 9, k = t & 511;
  const float* gib = gi + b * H3;
  const float* ghb = gh + b * H3;
  float r = 1.f / (1.f + __expf(-(gib[k] + ghb[k])));
  float z = 1.f / (1.f + __expf(-(gib[k + HH] + ghb[k + HH])));
  float n = tanhf(gib[k + 2 * HH] + r * ghb[k + 2 * HH]);
  float hn = (1.f - z) * n + z * h[t];
  cat[b * 1024 + k] = hn;
  out1[t] = hn;
  out3[t] = feed[t];
}

// ---------------- K3: lean streaming attention (TLP-first) --------------
// grid (NCH=32, BB) x 256. Wave w handles rows w+4j, j=0..15, of a 64-row
// chunk. 2-row ping-pong (16 reg floats); score stores stashed in LDS so
// the hot loop's vmcnt counts only enc loads. Target VGPR<=96 -> >=6
// blocks/CU resident (24+ waves) to cover HBM latency by TLP.
__device__ __forceinline__ void k3row(const float ev[8], const float hv[8],
                                      int idx, int lane,
                                      float* __restrict__ sds,
                                      float& m, float& s, float c[8]) {
  float d = 0.f;
#pragma unroll
  for (int i = 0; i < 8; ++i) d += hv[i] * ev[i];
  d = wsum(d);
  if (lane == 0) sds[idx] = d;  // LDS (lgkmcnt), not global
  float mn = fmaxf(m, d);
  float sc = __expf(m - mn);  // 1.0 when max unchanged; 0 on first row
  float wq = __expf(d - mn);
  s = s * sc + wq;
#pragma unroll
  for (int i = 0; i < 8; ++i) c[i] = c[i] * sc + wq * ev[i];
  m = mn;
}

__global__ __launch_bounds__(256) void k3_attn(
    const float* __restrict__ enc, const float* __restrict__ cat,
    float* __restrict__ scores, float* __restrict__ pm,
    float* __restrict__ ps, float* __restrict__ pc) {
  int b = blockIdx.y, ch = blockIdx.x;
  int w = threadIdx.x >> 6, lane = threadIdx.x & 63;
  int k0 = lane * 8;
  __shared__ float sds[CH_ROWS];
  __shared__ float sm[4], ssum[4];
  __shared__ float scx[4][512];

  float hv[8];
  ld8(cat + b * 1024 + k0, hv);

  const float* eb = enc + ((size_t)b * LL + ch * CH_ROWS) * HH;
  float m = -INFINITY, s = 0.f, c[8];
#pragma unroll
  for (int i = 0; i < 8; ++i) c[i] = 0.f;

  float evA[8], evB[8];
  ld8(eb + (size_t)w * HH + k0, evA);
  ld8(eb + (size_t)(w + 4) * HH + k0, evB);
#pragma unroll
  for (int j = 0; j < 16; j += 2) {
    if (j + 2 < 16) {
      k3row(evA, hv, w + 4 * j, lane, sds, m, s, c);
      ld8(eb + (size_t)(w + 4 * (j + 2)) * HH + k0, evA);
    } else {
      k3row(evA, hv, w + 4 * j, lane, sds, m, s, c);
    }
    if (j + 3 < 16) {
      k3row(evB, hv, w + 4 * (j + 1), lane, sds, m, s, c);
      ld8(eb + (size_t)(w + 4 * (j + 3)) * HH + k0, evB);
    } else {
      k3row(evB, hv, w + 4 * (j + 1), lane, sds, m, s, c);
    }
  }

  if (lane == 0) { sm[w] = m; ssum[w] = s; }
#pragma unroll
  for (int i = 0; i < 8; ++i) scx[w][k0 + i] = c[i];
  __syncthreads();

  int tid = threadIdx.x;
  // flush scores (coalesced, once)
  if (tid < CH_ROWS) scores[b * LL + ch * CH_ROWS + tid] = sds[tid];

  float mb = fmaxf(fmaxf(sm[0], sm[1]), fmaxf(sm[2], sm[3]));
  if (tid == 0) {
    float sb = 0.f;
#pragma unroll
    for (int w2 = 0; w2 < 4; ++w2) sb += ssum[w2] * __expf(sm[w2] - mb);
    pm[b * NCH + ch] = mb;
    ps[b * NCH + ch] = sb;
  }
  for (int k = tid; k < 512; k += 256) {
    float v = 0.f;
#pragma unroll
    for (int w2 = 0; w2 < 4; ++w2) v += scx[w2][k] * __expf(sm[w2] - mb);
    pc[(size_t)(b * NCH + ch) * 512 + k] = v;
  }
}

// ---------------- K45: combine -> ctx + attn-weights output -------------
__global__ __launch_bounds__(256) void k45_ctx(
    const float* __restrict__ pm, const float* __restrict__ ps,
    const float* __restrict__ pc, const float* __restrict__ scores,
    float* __restrict__ cat, float* __restrict__ out2) {
  int b = blockIdx.x;
  int tid = threadIdx.x;
  float mb = -INFINITY;
#pragma unroll
  for (int ch = 0; ch < NCH; ++ch) mb = fmaxf(mb, pm[b * NCH + ch]);
  float e[NCH];
  float den = 0.f;
#pragma unroll
  for (int ch = 0; ch < NCH; ++ch) {
    e[ch] = __expf(pm[b * NCH + ch] - mb);
    den += ps[b * NCH + ch] * e[ch];
  }
  for (int k = tid; k < 512; k += 256) {
    float v = 0.f;
#pragma unroll
    for (int ch = 0; ch < NCH; ++ch)
      v += pc[(size_t)(b * NCH + ch) * 512 + k] * e[ch];
    cat[b * 1024 + 512 + k] = v / den;
  }
  float inv = 1.f / den;
  for (int t = tid; t < LL; t += 256) {
    out2[b * LL + t] = __expf(scores[b * LL + t] - mb) * inv;
  }
}

// ---------------- K6: concat GEMV -> bf16 (proven) ----------------------
__global__ __launch_bounds__(256) void k6_concat(
    const float* __restrict__ cat, const float* __restrict__ Wc,
    const float* __restrict__ bc, unsigned short* __restrict__ co_bf) {
  int lane = threadIdx.x & 63;
  int wid = blockIdx.x * 4 + (threadIdx.x >> 6);  // 0..4095
  int k = wid >> 3, bg = wid & 7;
  float wv[16];
  ld16(Wc + (size_t)k * 1024 + lane * 16, wv);
  float bk = bc[k];
  for (int b = bg * 8; b < bg * 8 + 8; ++b) {
    float cv[16];
    ld16(cat + b * 1024 + lane * 16, cv);
    float d = 0.f;
#pragma unroll
    for (int i = 0; i < 16; ++i) d += wv[i] * cv[i];
    d = wsum(d);
    if (lane == 0) co_bf[b * HH + k] = f2bf(tanhf(d + bk));
  }
}

// ---------------- K7: MFMA output GEMM (proven R4 form) -----------------
__global__ __launch_bounds__(256) void k7_out(
    const unsigned short* __restrict__ co_bf, const float* __restrict__ Wo,
    const float* __restrict__ bo, float* __restrict__ out0) {
  int t = threadIdx.x;
  int lane = t & 63, w = t >> 6;
  int v0 = blockIdx.x * 64 + w * 16;
  int l15 = lane & 15;
  int kbase = (lane >> 4) * 8;
  int vrow = v0 + l15;
  const float* wrow = Wo + (size_t)vrow * HH;

  f32x4 acc[4];
#pragma unroll
  for (int j = 0; j < 4; ++j) acc[j] = (f32x4){0.f, 0.f, 0.f, 0.f};

  for (int ks = 0; ks < HH; ks += 32) {
    int k = ks + kbase;
    float4 wa = *(const float4*)(wrow + k);
    float4 wb = *(const float4*)(wrow + k + 4);
    union { unsigned short u[8]; bf16x8 v; } B;
    B.u[0] = f2bf(wa.x); B.u[1] = f2bf(wa.y);
    B.u[2] = f2bf(wa.z); B.u[3] = f2bf(wa.w);
    B.u[4] = f2bf(wb.x); B.u[5] = f2bf(wb.y);
    B.u[6] = f2bf(wb.z); B.u[7] = f2bf(wb.w);
#pragma unroll
    for (int j = 0; j < 4; ++j) {
      bf16x8 A = *(const bf16x8*)(co_bf + (size_t)(j * 16 + l15) * HH + k);
      acc[j] = __builtin_amdgcn_mfma_f32_16x16x32_bf16(A, B.v, acc[j], 0, 0, 0);
    }
  }

  float bias = bo[vrow];
#pragma unroll
  for (int j = 0; j < 4; ++j) {
    int b0 = j * 16 + (lane >> 4) * 4;
#pragma unroll
    for (int r = 0; r < 4; ++r) {
      out0[(size_t)(b0 + r) * VV + vrow] = acc[j][r] + bias;
    }
  }
}

extern "C" void kernel_launch(void* const* d_in, const int* in_sizes, int n_in,
                              void* d_out, int out_size, void* d_ws,
                              size_t ws_size, hipStream_t stream) {
  const int* seq = (const int*)d_in[0];
  const float* last_hidden = (const float*)d_in[1];
  const float* enc = (const float*)d_in[2];
  // d_in[3] encoder_labels unused
  const float* feed = (const float*)d_in[4];
  const float* emb = (const float*)d_in[5];
  const float* Wih = (const float*)d_in[6];
  const float* Whh = (const float*)d_in[7];
  const float* bih = (const float*)d_in[8];
  const float* bhh = (const float*)d_in[9];
  const float* Wc = (const float*)d_in[10];
  const float* bc = (const float*)d_in[11];
  const float* Wo = (const float*)d_in[12];
  const float* bo = (const float*)d_in[13];

  float* out = (float*)d_out;
  float* out0 = out;            // B*V
  float* out1 = out + 2048000;  // B*H
  float* out2 = out + 2080768;  // B*L
  float* out3 = out + 2211840;  // B*H

  float* ws = (float*)d_ws;
  float* gi = ws;                  // 98304
  float* gh = gi + 98304;          // 98304
  float* cat = gh + 98304;         // 65536 (h_new | context)
  float* scores = cat + 65536;     // 131072
  float* pm = scores + 131072;     // 2048
  float* ps = pm + 2048;           // 2048
  float* pc = ps + 2048;           // 1048576 (B*NCH*512)
  unsigned short* co_bf = (unsigned short*)(pc + 1048576);  // 32768 u16

  hipLaunchKernelGGL(k1_gates, dim3(384), dim3(256), 0, stream,
                     seq, last_hidden, emb, Wih, Whh, bih, bhh, gi, gh);
  hipLaunchKernelGGL(k2_hnew, dim3(128), dim3(256), 0, stream,
                     gi, gh, last_hidden, feed, cat, out1, out3);
  hipLaunchKernelGGL(k3_attn, dim3(NCH, BB), dim3(256), 0, stream,
                     enc, cat, scores, pm, ps, pc);
  hipLaunchKernelGGL(k45_ctx, dim3(64), dim3(256), 0, stream,
                     pm, ps, pc, scores, cat, out2);
  hipLaunchKernelGGL(k6_concat, dim3(1024), dim3(256), 0, stream,
                     cat, Wc, bc, co_bf);
  hipLaunchKernelGGL(k7_out, dim3(500), dim3(256), 0, stream,
                     co_bf, Wo, bo, out0);
}